// Round 13
// baseline (516.036 us; speedup 1.0000x reference)
//
#include <hip/hip_runtime.h>
#include <hip/hip_fp16.h>
#include <cstddef>

// ---------------------------------------------------------------------------
// Het_Agg: 4-relation GNN aggregation + attention combine + linear + L2 norm
// fp32 in/out; h staged as fp8 e4m3 (HW cvt).
// CSR build: counting sort with 512-node buckets.
//   binGemm (fused): block-aggregated binning into per-bucket runs || h-gemm
//   csr2: per bucket: self-allocated window, LDS hist(512) -> offc{beg,cnt},
//         scatter records direct to ushort sorted[]
// gatherGemm (fused): per block of 64 nodes: 4 waves gather+attention-combine
//   16 nodes each into an LDS comb tile (never hits global), then the block
//   runs the [xn|comb] @ Wl fp16-MFMA + L2-norm epilogue. The MFMA work of
//   early blocks overlaps the latency-bound gather of co-resident blocks.
// ---------------------------------------------------------------------------

#define BN1       512    // nodes per bucket
#define BN1_SHIFT 9
#define BCAP1     20480  // mean 16384 @ E=1.6M,N=50K; +32 sigma margin
#define NB1MAX    128    // max buckets/relation (N <= 65536)
#define BLK_E     16384  // edges per binning block

struct IP4 { const int* p[4]; };
struct FP4 { const float* p[4]; };

typedef _Float16 half8 __attribute__((ext_vector_type(8)));
typedef float f32x4 __attribute__((ext_vector_type(4)));
typedef float f32x2 __attribute__((ext_vector_type(2)));

// prep: Wt[r][c][k]=fp16(W_r[k][c]); Wlt[c][k]=fp16(Wl[k][c]); zero bcur+gcur
__global__ __launch_bounds__(256) void prep0_k(FP4 Wm, const float* __restrict__ Wl,
                                               __half* __restrict__ Wt,
                                               __half* __restrict__ Wlt,
                                               int* __restrict__ bcur, int nzero) {
    const int b = blockIdx.x, t = threadIdx.x;
    if (b < 256) {
        int r = b >> 6;
        int i = (b & 63) * 256 + t;           // 0..16383
        int k = i & 127, c = i >> 7;
        Wt[(size_t)r * 16384 + c * 128 + k] = __float2half(Wm.p[r][(size_t)k * 128 + c]);
    } else if (b < 384) {
        int i = (b - 256) * 256 + t;          // 0..32767
        int k = i & 255, c = i >> 8;
        Wlt[(size_t)c * 256 + k] = __float2half(Wl[(size_t)k * 128 + c]);
    } else {
        for (int i = (b - 384) * 256 + t; i < nzero; i += 64 * 256) bcur[i] = 0;
    }
}

// FUSED: 512-node-bucket binning (x < 4*binb)  ||  h = relu(xW+b) -> fp8 gemm
__global__ __launch_bounds__(256) void binGemm_k(IP4 ed, int4 Ev, int* __restrict__ bcur,
                                                 int* __restrict__ staging, int nb1, int binb,
                                                 FP4 X, const __half* __restrict__ Wt,
                                                 FP4 Bv, unsigned char* __restrict__ H8,
                                                 int M, int gb) {
    __shared__ int ldsu[4096];   // 16 KB union: bin{hist,curs} / gemm{As}
    const int t = threadIdx.x;
    const int x = blockIdx.x;

    if (x < 4 * binb) {
        // ------------------------- bin role -------------------------
        const int r = x / binb;
        const int bx = x - r * binb;
        const int E = (r == 0) ? Ev.x : (r == 1) ? Ev.y : (r == 2) ? Ev.z : Ev.w;
        const int e0 = bx * BLK_E;
        if (e0 >= E) return;
        const int e1 = min(e0 + BLK_E, E);
        const int* es = ed.p[r];
        const int* et = es + E;
        int* bc = bcur + (size_t)r * nb1 * 16;
        int* stg = staging + (size_t)r * nb1 * BCAP1;
        int* hist = ldsu;
        int* curs = ldsu + NB1MAX;

        for (int b = t; b < nb1; b += 256) hist[b] = 0;
        __syncthreads();
        {
            const int n = e1 - e0;
            const int n4 = n >> 2;
            const int4* s4 = reinterpret_cast<const int4*>(es + e0);
            for (int i = t; i < n4; i += 256) {
                int4 s = s4[i];
                atomicAdd(&hist[s.x >> BN1_SHIFT], 1);
                atomicAdd(&hist[s.y >> BN1_SHIFT], 1);
                atomicAdd(&hist[s.z >> BN1_SHIFT], 1);
                atomicAdd(&hist[s.w >> BN1_SHIFT], 1);
            }
            for (int i = e0 + n4 * 4 + t; i < e1; i += 256)
                atomicAdd(&hist[es[i] >> BN1_SHIFT], 1);
        }
        __syncthreads();
        for (int b = t; b < nb1; b += 256) {
            int c = hist[b];
            curs[b] = c ? atomicAdd(&bc[b * 16], c) : 0;
        }
        __syncthreads();
        {
            const int n = e1 - e0;
            const int n4 = n >> 2;
            const int4* s4 = reinterpret_cast<const int4*>(es + e0);
            const int4* t4 = reinterpret_cast<const int4*>(et + e0);
            for (int i = t; i < n4; i += 256) {
                int4 s = s4[i];
                int4 tg = t4[i];
                int b, p;
                b = s.x >> BN1_SHIFT; p = atomicAdd(&curs[b], 1);
                if (p < BCAP1) stg[(size_t)b * BCAP1 + p] = ((s.x & 511) << 16) | tg.x;
                b = s.y >> BN1_SHIFT; p = atomicAdd(&curs[b], 1);
                if (p < BCAP1) stg[(size_t)b * BCAP1 + p] = ((s.y & 511) << 16) | tg.y;
                b = s.z >> BN1_SHIFT; p = atomicAdd(&curs[b], 1);
                if (p < BCAP1) stg[(size_t)b * BCAP1 + p] = ((s.z & 511) << 16) | tg.z;
                b = s.w >> BN1_SHIFT; p = atomicAdd(&curs[b], 1);
                if (p < BCAP1) stg[(size_t)b * BCAP1 + p] = ((s.w & 511) << 16) | tg.w;
            }
            for (int i = e0 + n4 * 4 + t; i < e1; i += 256) {
                int s = es[i];
                int b = s >> BN1_SHIFT;
                int p = atomicAdd(&curs[b], 1);
                if (p < BCAP1) stg[(size_t)b * BCAP1 + p] = ((s & 511) << 16) | et[i];
            }
        }
    } else {
        // ------------------------- gemm role ------------------------
        const int g = x - 4 * binb;
        const int r = g / gb;
        const int bx = g - r * gb;
        const float* A = X.p[r];
        const __half* Wr = Wt + (size_t)r * 16384;
        const float* bias = Bv.p[r];
        unsigned char* Hr = H8 + (size_t)r * M * 128;
        const int n0 = bx * 64;
        char* AsB = reinterpret_cast<char*>(ldsu);

        for (int s = t; s < 1024; s += 256) {
            int row = s >> 4, c8 = (s & 15) << 3;
            int grow = n0 + row;
            float4 v0 = make_float4(0.f, 0.f, 0.f, 0.f), v1 = v0;
            if (grow < M) {
                v0 = *reinterpret_cast<const float4*>(&A[(size_t)grow * 128 + c8]);
                v1 = *reinterpret_cast<const float4*>(&A[(size_t)grow * 128 + c8 + 4]);
            }
            half8 hv;
            hv[0] = (_Float16)v0.x; hv[1] = (_Float16)v0.y;
            hv[2] = (_Float16)v0.z; hv[3] = (_Float16)v0.w;
            hv[4] = (_Float16)v1.x; hv[5] = (_Float16)v1.y;
            hv[6] = (_Float16)v1.z; hv[7] = (_Float16)v1.w;
            int byte = (row * 256 + c8 * 2) ^ ((row & 7) << 4);
            *reinterpret_cast<half8*>(AsB + byte) = hv;
        }
        __syncthreads();

        const int w = t >> 6, lane = t & 63;
        const int r0 = (w & 1) * 32, c0 = (w >> 1) * 64;
        const int lr = lane & 15;
        const int lk = (lane >> 4) * 8;

        f32x4 acc[2][4] = {};
        #pragma unroll
        for (int k0 = 0; k0 < 128; k0 += 32) {
            half8 af[2], bf[4];
            #pragma unroll
            for (int mi = 0; mi < 2; ++mi) {
                int row = r0 + mi * 16 + lr;
                int byte = (row * 256 + (k0 + lk) * 2) ^ ((row & 7) << 4);
                af[mi] = *reinterpret_cast<const half8*>(AsB + byte);
            }
            #pragma unroll
            for (int ni = 0; ni < 4; ++ni) {
                int col = c0 + ni * 16 + lr;
                bf[ni] = *reinterpret_cast<const half8*>(&Wr[(size_t)col * 128 + k0 + lk]);
            }
            #pragma unroll
            for (int mi = 0; mi < 2; ++mi)
                #pragma unroll
                for (int ni = 0; ni < 4; ++ni)
                    acc[mi][ni] = __builtin_amdgcn_mfma_f32_16x16x32_f16(af[mi], bf[ni],
                                                                         acc[mi][ni], 0, 0, 0);
        }
        __syncthreads();
        unsigned char* ht = reinterpret_cast<unsigned char*>(AsB);  // 64x128 bytes
        #pragma unroll
        for (int ni = 0; ni < 4; ++ni) {
            int col = c0 + ni * 16 + lr;
            float bb = bias[col];
            #pragma unroll
            for (int mi = 0; mi < 2; ++mi) {
                #pragma unroll
                for (int j = 0; j < 4; ++j) {
                    int row = r0 + mi * 16 + (lane >> 4) * 4 + j;
                    float y = fmaxf(acc[mi][ni][j] + bb, 0.f);
                    int e = __builtin_amdgcn_cvt_pk_fp8_f32(y, 0.f, 0, false);
                    ht[row * 128 + col] = (unsigned char)e;
                }
            }
        }
        __syncthreads();
        {
            int row = t >> 2, cb = (t & 3) * 32;
            int grow = n0 + row;
            if (grow < M) {
                const int4* p = reinterpret_cast<const int4*>(ht + row * 128 + cb);
                int4 a = p[0], b = p[1];
                int4* q = reinterpret_cast<int4*>(Hr + (size_t)grow * 128 + cb);
                q[0] = a; q[1] = b;
            }
        }
    }
}

// per 512-node bucket: self-allocated window, LDS hist -> offc{beg,cnt},
// scatter records direct to ushort sorted[] (window is L2-local)
__global__ __launch_bounds__(256) void csr2_k(const int* __restrict__ staging,
                                              const int* __restrict__ bcur,
                                              int* __restrict__ gcur,
                                              int2* __restrict__ offc,
                                              unsigned short* __restrict__ sorted,
                                              int nb1, int N) {
    const int r = blockIdx.y;
    const int b = blockIdx.x;
    const int gi = r * nb1 + b;
    const int sz = min(bcur[(size_t)gi * 16], BCAP1);
    const int* stg = staging + (size_t)gi * BCAP1;
    const int nbase = b * BN1;
    const int t = threadIdx.x;
    const int lane = t & 63, wid = t >> 6;

    __shared__ int hist[BN1];
    __shared__ int cur[BN1];
    __shared__ int wsum[4];
    __shared__ int base_s;

    if (t == 0) base_s = atomicAdd(gcur, sz);
    hist[t] = 0;
    hist[t + 256] = 0;
    __syncthreads();
    {
        const int sz4 = sz >> 2;
        const int4* s4 = reinterpret_cast<const int4*>(stg);
        for (int i = t; i < sz4; i += 256) {
            int4 v = s4[i];
            atomicAdd(&hist[((unsigned)v.x) >> 16], 1);
            atomicAdd(&hist[((unsigned)v.y) >> 16], 1);
            atomicAdd(&hist[((unsigned)v.z) >> 16], 1);
            atomicAdd(&hist[((unsigned)v.w) >> 16], 1);
        }
        for (int i = sz4 * 4 + t; i < sz; i += 256)
            atomicAdd(&hist[((unsigned)stg[i]) >> 16], 1);
    }
    __syncthreads();
    const int base = base_s;
    int v0 = hist[2 * t], v1 = hist[2 * t + 1];
    int ps = v0 + v1;
    int incl = ps;
    #pragma unroll
    for (int d = 1; d < 64; d <<= 1) {
        int x = __shfl_up(incl, d);
        if (lane >= d) incl += x;
    }
    if (lane == 63) wsum[wid] = incl;
    __syncthreads();
    if (t == 0) {
        int a = 0;
        #pragma unroll
        for (int i = 0; i < 4; ++i) { int x = wsum[i]; wsum[i] = a; a += x; }
    }
    __syncthreads();
    int e0 = wsum[wid] + incl - ps;
    cur[2 * t] = e0;
    cur[2 * t + 1] = e0 + v0;
    {
        int n0 = nbase + 2 * t;
        if (n0 < N) offc[(size_t)r * N + n0] = make_int2(base + e0, v0);
        if (n0 + 1 < N) offc[(size_t)r * N + n0 + 1] = make_int2(base + e0 + v0, v1);
    }
    __syncthreads();
    {
        const int sz4 = sz >> 2;
        const int4* s4 = reinterpret_cast<const int4*>(stg);
        for (int i = t; i < sz4; i += 256) {
            int4 v = s4[i];
            int p;
            p = atomicAdd(&cur[((unsigned)v.x) >> 16], 1);
            sorted[base + p] = (unsigned short)(v.x & 0xFFFF);
            p = atomicAdd(&cur[((unsigned)v.y) >> 16], 1);
            sorted[base + p] = (unsigned short)(v.y & 0xFFFF);
            p = atomicAdd(&cur[((unsigned)v.z) >> 16], 1);
            sorted[base + p] = (unsigned short)(v.z & 0xFFFF);
            p = atomicAdd(&cur[((unsigned)v.w) >> 16], 1);
            sorted[base + p] = (unsigned short)(v.w & 0xFFFF);
        }
        for (int i = sz4 * 4 + t; i < sz; i += 256) {
            int rec = stg[i];
            int p = atomicAdd(&cur[((unsigned)rec) >> 16], 1);
            sorted[base + p] = (unsigned short)(rec & 0xFFFF);
        }
    }
}

// FUSED gather + output gemm. Block = 64 nodes, 4 waves.
// Phase 1: wave w gathers nodes [w*16, w*16+16): mean-aggregate 4 relations
//   (fp8 rows, 16 lanes x 8B per edge, 8 edges/step, bpermute broadcast,
//   id-block prefetch) + attention combine -> fp16 comb row in LDS (swizzled).
// Phase 2: y = relu([xn|comb] @ Wl + bl); out = y / max(||y||,1e-12) via
//   fp16 MFMA; comb read from LDS, xn staged into the same LDS buffer.
__global__ __launch_bounds__(256) void gatherGemm_k(const unsigned char* __restrict__ H8,
                                                    const float* __restrict__ xn,
                                                    const float* __restrict__ u,
                                                    const int2* __restrict__ offc,
                                                    const unsigned short* __restrict__ sorted,
                                                    const __half* __restrict__ Wlt,
                                                    const float* __restrict__ bias,
                                                    float* __restrict__ out, int N) {
    __shared__ __half Cs[64 * 128];   // 16 KB tile: comb (phase A) then xn (phase B)
    __shared__ float rowss[64];
    const int t = threadIdx.x;
    const int n0 = blockIdx.x * 64;
    char* CsB = reinterpret_cast<char*>(Cs);
    const int w = t >> 6, lane = t & 63;
    const int q = lane >> 4;      // quadrant: edge slot
    const int c = lane & 15;      // col group
    if (t < 64) rowss[t] = 0.f;

    float4 ua0 = reinterpret_cast<const float4*>(u)[c * 2];
    float4 ua1 = reinterpret_cast<const float4*>(u)[c * 2 + 1];
    float2 ux = *reinterpret_cast<const float2*>(&u[128 + lane * 2]);

    // ---------------- phase 1: gather 16 nodes per wave ----------------
    #pragma unroll 1
    for (int ln = w * 16; ln < w * 16 + 16; ++ln) {
        const int node = n0 + ln;
        const int byteo = (ln * 256 + c * 16) ^ ((ln & 7) << 4);
        if (node < N) {
            float2 x2 = *reinterpret_cast<const float2*>(&xn[(size_t)node * 128 + lane * 2]);
            float px = x2.x * ux.x + x2.y * ux.y;
            #pragma unroll
            for (int m = 1; m < 64; m <<= 1) px += __shfl_xor(px, m);

            float a[4][8];
            float invd[4], pr[4];
            #pragma unroll
            for (int r = 0; r < 4; ++r) {
                const int2 oc = offc[(size_t)r * N + node];
                const int beg = oc.x, cnt = oc.y;
                const unsigned char* hr = H8 + (size_t)r * N * 128;
                const unsigned short* sl = sorted + beg;
                f32x2 s01 = {0.f, 0.f}, s23 = {0.f, 0.f}, s45 = {0.f, 0.f}, s67 = {0.f, 0.f};
                int my = (lane < cnt) ? (int)sl[lane] : 0;
                for (int j0 = 0; j0 < cnt; j0 += 64) {
                    const int m = min(64, cnt - j0);
                    int my_next = (j0 + 64 + lane < cnt) ? (int)sl[j0 + 64 + lane] : 0;
                    int j = 0;
                    for (; j + 8 <= m; j += 8) {
                        int tg0 = __shfl(my, j + q);
                        int tg1 = __shfl(my, j + q + 4);
                        uint2 raw0 = reinterpret_cast<const uint2*>(hr + (size_t)tg0 * 128)[c];
                        uint2 raw1 = reinterpret_cast<const uint2*>(hr + (size_t)tg1 * 128)[c];
                        s01 += __builtin_amdgcn_cvt_pk_f32_fp8((int)raw0.x, false);
                        s23 += __builtin_amdgcn_cvt_pk_f32_fp8((int)raw0.x, true);
                        s45 += __builtin_amdgcn_cvt_pk_f32_fp8((int)raw0.y, false);
                        s67 += __builtin_amdgcn_cvt_pk_f32_fp8((int)raw0.y, true);
                        s01 += __builtin_amdgcn_cvt_pk_f32_fp8((int)raw1.x, false);
                        s23 += __builtin_amdgcn_cvt_pk_f32_fp8((int)raw1.x, true);
                        s45 += __builtin_amdgcn_cvt_pk_f32_fp8((int)raw1.y, false);
                        s67 += __builtin_amdgcn_cvt_pk_f32_fp8((int)raw1.y, true);
                    }
                    for (; j < m; j += 4) {
                        int jj = j + q;
                        int tg = __shfl(my, min(jj, m - 1));
                        if (jj < m) {
                            uint2 raw = reinterpret_cast<const uint2*>(hr + (size_t)tg * 128)[c];
                            s01 += __builtin_amdgcn_cvt_pk_f32_fp8((int)raw.x, false);
                            s23 += __builtin_amdgcn_cvt_pk_f32_fp8((int)raw.x, true);
                            s45 += __builtin_amdgcn_cvt_pk_f32_fp8((int)raw.y, false);
                            s67 += __builtin_amdgcn_cvt_pk_f32_fp8((int)raw.y, true);
                        }
                    }
                    my = my_next;
                }
                float s[8] = {s01[0], s01[1], s23[0], s23[1], s45[0], s45[1], s67[0], s67[1]};
                #pragma unroll
                for (int k = 0; k < 8; ++k) {
                    s[k] += __shfl_xor(s[k], 16);
                    s[k] += __shfl_xor(s[k], 32);
                }
                float dp = s[0] * ua0.x + s[1] * ua0.y + s[2] * ua0.z + s[3] * ua0.w
                         + s[4] * ua1.x + s[5] * ua1.y + s[6] * ua1.z + s[7] * ua1.w;
                #pragma unroll
                for (int m = 1; m < 16; m <<= 1) dp += __shfl_xor(dp, m);
                pr[r] = dp;
                invd[r] = 1.0f / fmaxf((float)cnt, 1.0f);
                #pragma unroll
                for (int k = 0; k < 8; ++k) a[r][k] = s[k];
            }
            float wgt[4], denom = 0.f;
            #pragma unroll
            for (int r = 0; r < 4; ++r) {
                float sc = pr[r] * invd[r] + px;
                float z = (sc > 0.f) ? sc : 0.01f * sc;   // leaky_relu 0.01
                wgt[r] = expf(z);
                denom += wgt[r];
            }
            float cf[4];
            #pragma unroll
            for (int r = 0; r < 4; ++r) cf[r] = (wgt[r] / denom) * invd[r];
            if (q == 0) {
                half8 o;
                #pragma unroll
                for (int k = 0; k < 8; ++k)
                    o[k] = (_Float16)(cf[0] * a[0][k] + cf[1] * a[1][k] +
                                      cf[2] * a[2][k] + cf[3] * a[3][k]);
                *reinterpret_cast<half8*>(CsB + byteo) = o;
            }
        } else if (q == 0) {
            half8 z = {};
            *reinterpret_cast<half8*>(CsB + byteo) = z;
        }
    }
    __syncthreads();

    // ---------------- phase 2: output gemm + L2 norm ----------------
    const int r0 = (w & 1) * 32, c0 = (w >> 1) * 64;
    const int lr = lane & 15;
    const int lk = (lane >> 4) * 8;

    f32x4 acc[2][4] = {};
    // phase A: comb (in Cs) x Wl rows [128,256)
    #pragma unroll
    for (int k0 = 0; k0 < 128; k0 += 32) {
        half8 af[2], bf[4];
        #pragma unroll
        for (int mi = 0; mi < 2; ++mi) {
            int row = r0 + mi * 16 + lr;
            int byte = (row * 256 + (k0 + lk) * 2) ^ ((row & 7) << 4);
            af[mi] = *reinterpret_cast<const half8*>(CsB + byte);
        }
        #pragma unroll
        for (int ni = 0; ni < 4; ++ni) {
            int col = c0 + ni * 16 + lr;
            bf[ni] = *reinterpret_cast<const half8*>(&Wlt[(size_t)col * 256 + 128 + k0 + lk]);
        }
        #pragma unroll
        for (int mi = 0; mi < 2; ++mi)
            #pragma unroll
            for (int ni = 0; ni < 4; ++ni)
                acc[mi][ni] = __builtin_amdgcn_mfma_f32_16x16x32_f16(af[mi], bf[ni],
                                                                     acc[mi][ni], 0, 0, 0);
    }
    __syncthreads();
    // stage xn tile (fp32 -> fp16, swizzled) into Cs
    for (int s = t; s < 1024; s += 256) {
        int row = s >> 4, c8 = (s & 15) << 3;
        int grow = n0 + row;
        float4 v0 = make_float4(0.f, 0.f, 0.f, 0.f), v1 = v0;
        if (grow < N) {
            v0 = *reinterpret_cast<const float4*>(&xn[(size_t)grow * 128 + c8]);
            v1 = *reinterpret_cast<const float4*>(&xn[(size_t)grow * 128 + c8 + 4]);
        }
        half8 hv;
        hv[0] = (_Float16)v0.x; hv[1] = (_Float16)v0.y;
        hv[2] = (_Float16)v0.z; hv[3] = (_Float16)v0.w;
        hv[4] = (_Float16)v1.x; hv[5] = (_Float16)v1.y;
        hv[6] = (_Float16)v1.z; hv[7] = (_Float16)v1.w;
        int byte = (row * 256 + c8 * 2) ^ ((row & 7) << 4);
        *reinterpret_cast<half8*>(CsB + byte) = hv;
    }
    __syncthreads();
    // phase B: xn x Wl rows [0,128)
    #pragma unroll
    for (int k0 = 0; k0 < 128; k0 += 32) {
        half8 af[2], bf[4];
        #pragma unroll
        for (int mi = 0; mi < 2; ++mi) {
            int row = r0 + mi * 16 + lr;
            int byte = (row * 256 + (k0 + lk) * 2) ^ ((row & 7) << 4);
            af[mi] = *reinterpret_cast<const half8*>(CsB + byte);
        }
        #pragma unroll
        for (int ni = 0; ni < 4; ++ni) {
            int col = c0 + ni * 16 + lr;
            bf[ni] = *reinterpret_cast<const half8*>(&Wlt[(size_t)col * 256 + k0 + lk]);
        }
        #pragma unroll
        for (int mi = 0; mi < 2; ++mi)
            #pragma unroll
            for (int ni = 0; ni < 4; ++ni)
                acc[mi][ni] = __builtin_amdgcn_mfma_f32_16x16x32_f16(af[mi], bf[ni],
                                                                     acc[mi][ni], 0, 0, 0);
    }
    // epilogue: bias + relu + row L2-norm + store
    float bbv[4];
    #pragma unroll
    for (int ni = 0; ni < 4; ++ni) bbv[ni] = bias[c0 + ni * 16 + lr];
    #pragma unroll
    for (int mi = 0; mi < 2; ++mi) {
        #pragma unroll
        for (int j = 0; j < 4; ++j) {
            int row_l = r0 + mi * 16 + (lane >> 4) * 4 + j;
            float ss = 0.f;
            #pragma unroll
            for (int ni = 0; ni < 4; ++ni) {
                float y = fmaxf(acc[mi][ni][j] + bbv[ni], 0.f);
                ss += y * y;
            }
            ss += __shfl_xor(ss, 1); ss += __shfl_xor(ss, 2);
            ss += __shfl_xor(ss, 4); ss += __shfl_xor(ss, 8);
            if (lr == 0) atomicAdd(&rowss[row_l], ss);
        }
    }
    __syncthreads();
    #pragma unroll
    for (int mi = 0; mi < 2; ++mi) {
        #pragma unroll
        for (int j = 0; j < 4; ++j) {
            int row_l = r0 + mi * 16 + (lane >> 4) * 4 + j;
            int grow = n0 + row_l;
            if (grow < N) {
                float inv = 1.0f / fmaxf(sqrtf(rowss[row_l]), 1e-12f);
                #pragma unroll
                for (int ni = 0; ni < 4; ++ni) {
                    float y = fmaxf(acc[mi][ni][j] + bbv[ni], 0.f);
                    out[(size_t)grow * 128 + c0 + ni * 16 + lr] = y * inv;
                }
            }
        }
    }
}

extern "C" void kernel_launch(void* const* d_in, const int* in_sizes, int n_in,
                              void* d_out, int out_size, void* d_ws, size_t ws_size,
                              hipStream_t stream) {
    FP4 X  = {{(const float*)d_in[0], (const float*)d_in[2],
               (const float*)d_in[4], (const float*)d_in[6]}};
    IP4 ED = {{(const int*)d_in[1], (const int*)d_in[3],
               (const int*)d_in[5], (const int*)d_in[7]}};
    const float* xn = (const float*)d_in[8];
    FP4 Wm = {{(const float*)d_in[10], (const float*)d_in[12],
               (const float*)d_in[14], (const float*)d_in[16]}};
    FP4 Bv = {{(const float*)d_in[11], (const float*)d_in[13],
               (const float*)d_in[15], (const float*)d_in[17]}};
    const float* u  = (const float*)d_in[18];
    const float* Wl = (const float*)d_in[19];
    const float* bl = (const float*)d_in[20];
    float* out = (float*)d_out;

    const int N = in_sizes[8] / 128;
    int E[4];
    for (int r = 0; r < 4; ++r) E[r] = in_sizes[1 + 2 * r] / 2;
    const int4 Ev = make_int4(E[0], E[1], E[2], E[3]);
    const int nb1 = (N + BN1 - 1) / BN1;
    int maxE = 0;
    for (int r = 0; r < 4; ++r) maxE = (E[r] > maxE) ? E[r] : maxE;

    // ws layout
    unsigned char* h8 = (unsigned char*)d_ws;                    // 4*N*128 bytes
    int*   staging = (int*)(h8 + (size_t)4 * N * 128);           // 4*nb1*BCAP1 ints
    __half* Wt     = (__half*)(staging + (size_t)4 * nb1 * BCAP1); // 4*16384 halfs
    __half* Wlt    = Wt + (size_t)4 * 16384;                     // 128*256 halfs
    int2* offc   = (int2*)(Wlt + (size_t)128 * 256);             // 4*N int2
    int* bcur    = (int*)(offc + (size_t)4 * N);                 // 4*nb1*16
    int* gcur    = bcur + (size_t)4 * nb1 * 16;                  // 16 (pad)
    unsigned short* sorted = (unsigned short*)(gcur + 16);       // sumE ushorts

    const int gb = (N + 63) / 64;
    const int binb = (maxE + BLK_E - 1) / BLK_E;

    prep0_k<<<448, 256, 0, stream>>>(Wm, Wl, Wt, Wlt, bcur, 4 * nb1 * 16 + 16);
    binGemm_k<<<4 * binb + 4 * gb, 256, 0, stream>>>(ED, Ev, bcur, staging, nb1, binb,
                                                     X, Wt, Bv, h8, N, gb);
    csr2_k<<<dim3(nb1, 4), 256, 0, stream>>>(staging, bcur, gcur, offc, sorted, nb1, N);
    gatherGemm_k<<<gb, 256, 0, stream>>>(h8, xn, u, offc, sorted, Wlt, bl, out, N);
}

// Round 14
// 307.746 us; speedup vs baseline: 1.6768x; 1.6768x over previous
//
#include <hip/hip_runtime.h>
#include <hip/hip_fp16.h>
#include <cstddef>

// ---------------------------------------------------------------------------
// Het_Agg: 4-relation GNN aggregation + attention combine + linear + L2 norm
// fp32 in/out; h staged as fp8 e4m3 (HW cvt), comb staged fp16.
// CSR build: counting sort with 512-node buckets.
//   binGemm (fused): block-aggregated binning into per-bucket runs  ||  h-gemm
//   csr2: per bucket: self-allocated window (global cursor), LDS hist(512)
//         -> offc{beg,cnt}, scatter records direct to ushort sorted[]
// gather: one wave/node, 16 lanes x 8B fp8 per edge row, 16 edges per main
// step (4 bpermute-broadcast ids, 4 row loads in flight), id-block prefetch,
// packed f32x2 accumulation.
// ---------------------------------------------------------------------------

#define BN1       512    // nodes per bucket
#define BN1_SHIFT 9
#define BCAP1     20480  // mean 16384 @ E=1.6M,N=50K; +32 sigma margin
#define NB1MAX    128    // max buckets/relation (N <= 65536)
#define BLK_E     16384  // edges per binning block

struct IP4 { const int* p[4]; };
struct FP4 { const float* p[4]; };

typedef _Float16 half8 __attribute__((ext_vector_type(8)));
typedef float f32x4 __attribute__((ext_vector_type(4)));
typedef float f32x2 __attribute__((ext_vector_type(2)));

// prep: Wt[r][c][k]=fp16(W_r[k][c]); Wlt[c][k]=fp16(Wl[k][c]); zero bcur+gcur
__global__ __launch_bounds__(256) void prep0_k(FP4 Wm, const float* __restrict__ Wl,
                                               __half* __restrict__ Wt,
                                               __half* __restrict__ Wlt,
                                               int* __restrict__ bcur, int nzero) {
    const int b = blockIdx.x, t = threadIdx.x;
    if (b < 256) {
        int r = b >> 6;
        int i = (b & 63) * 256 + t;           // 0..16383
        int k = i & 127, c = i >> 7;
        Wt[(size_t)r * 16384 + c * 128 + k] = __float2half(Wm.p[r][(size_t)k * 128 + c]);
    } else if (b < 384) {
        int i = (b - 256) * 256 + t;          // 0..32767
        int k = i & 255, c = i >> 8;
        Wlt[(size_t)c * 256 + k] = __float2half(Wl[(size_t)k * 128 + c]);
    } else {
        for (int i = (b - 384) * 256 + t; i < nzero; i += 64 * 256) bcur[i] = 0;
    }
}

// FUSED: 512-node-bucket binning (x < 4*binb)  ||  h = relu(xW+b) -> fp8 gemm
__global__ __launch_bounds__(256) void binGemm_k(IP4 ed, int4 Ev, int* __restrict__ bcur,
                                                 int* __restrict__ staging, int nb1, int binb,
                                                 FP4 X, const __half* __restrict__ Wt,
                                                 FP4 Bv, unsigned char* __restrict__ H8,
                                                 int M, int gb) {
    __shared__ int ldsu[4096];   // 16 KB union: bin{hist,curs} / gemm{As}
    const int t = threadIdx.x;
    const int x = blockIdx.x;

    if (x < 4 * binb) {
        // ------------------------- bin role -------------------------
        const int r = x / binb;
        const int bx = x - r * binb;
        const int E = (r == 0) ? Ev.x : (r == 1) ? Ev.y : (r == 2) ? Ev.z : Ev.w;
        const int e0 = bx * BLK_E;
        if (e0 >= E) return;
        const int e1 = min(e0 + BLK_E, E);
        const int* es = ed.p[r];
        const int* et = es + E;
        int* bc = bcur + (size_t)r * nb1 * 16;
        int* stg = staging + (size_t)r * nb1 * BCAP1;
        int* hist = ldsu;
        int* curs = ldsu + NB1MAX;

        for (int b = t; b < nb1; b += 256) hist[b] = 0;
        __syncthreads();
        {
            const int n = e1 - e0;
            const int n4 = n >> 2;
            const int4* s4 = reinterpret_cast<const int4*>(es + e0);
            for (int i = t; i < n4; i += 256) {
                int4 s = s4[i];
                atomicAdd(&hist[s.x >> BN1_SHIFT], 1);
                atomicAdd(&hist[s.y >> BN1_SHIFT], 1);
                atomicAdd(&hist[s.z >> BN1_SHIFT], 1);
                atomicAdd(&hist[s.w >> BN1_SHIFT], 1);
            }
            for (int i = e0 + n4 * 4 + t; i < e1; i += 256)
                atomicAdd(&hist[es[i] >> BN1_SHIFT], 1);
        }
        __syncthreads();
        for (int b = t; b < nb1; b += 256) {
            int c = hist[b];
            curs[b] = c ? atomicAdd(&bc[b * 16], c) : 0;
        }
        __syncthreads();
        {
            const int n = e1 - e0;
            const int n4 = n >> 2;
            const int4* s4 = reinterpret_cast<const int4*>(es + e0);
            const int4* t4 = reinterpret_cast<const int4*>(et + e0);
            for (int i = t; i < n4; i += 256) {
                int4 s = s4[i];
                int4 tg = t4[i];
                int b, p;
                b = s.x >> BN1_SHIFT; p = atomicAdd(&curs[b], 1);
                if (p < BCAP1) stg[(size_t)b * BCAP1 + p] = ((s.x & 511) << 16) | tg.x;
                b = s.y >> BN1_SHIFT; p = atomicAdd(&curs[b], 1);
                if (p < BCAP1) stg[(size_t)b * BCAP1 + p] = ((s.y & 511) << 16) | tg.y;
                b = s.z >> BN1_SHIFT; p = atomicAdd(&curs[b], 1);
                if (p < BCAP1) stg[(size_t)b * BCAP1 + p] = ((s.z & 511) << 16) | tg.z;
                b = s.w >> BN1_SHIFT; p = atomicAdd(&curs[b], 1);
                if (p < BCAP1) stg[(size_t)b * BCAP1 + p] = ((s.w & 511) << 16) | tg.w;
            }
            for (int i = e0 + n4 * 4 + t; i < e1; i += 256) {
                int s = es[i];
                int b = s >> BN1_SHIFT;
                int p = atomicAdd(&curs[b], 1);
                if (p < BCAP1) stg[(size_t)b * BCAP1 + p] = ((s & 511) << 16) | et[i];
            }
        }
    } else {
        // ------------------------- gemm role ------------------------
        const int g = x - 4 * binb;
        const int r = g / gb;
        const int bx = g - r * gb;
        const float* A = X.p[r];
        const __half* Wr = Wt + (size_t)r * 16384;
        const float* bias = Bv.p[r];
        unsigned char* Hr = H8 + (size_t)r * M * 128;
        const int n0 = bx * 64;
        char* AsB = reinterpret_cast<char*>(ldsu);

        for (int s = t; s < 1024; s += 256) {
            int row = s >> 4, c8 = (s & 15) << 3;
            int grow = n0 + row;
            float4 v0 = make_float4(0.f, 0.f, 0.f, 0.f), v1 = v0;
            if (grow < M) {
                v0 = *reinterpret_cast<const float4*>(&A[(size_t)grow * 128 + c8]);
                v1 = *reinterpret_cast<const float4*>(&A[(size_t)grow * 128 + c8 + 4]);
            }
            half8 hv;
            hv[0] = (_Float16)v0.x; hv[1] = (_Float16)v0.y;
            hv[2] = (_Float16)v0.z; hv[3] = (_Float16)v0.w;
            hv[4] = (_Float16)v1.x; hv[5] = (_Float16)v1.y;
            hv[6] = (_Float16)v1.z; hv[7] = (_Float16)v1.w;
            int byte = (row * 256 + c8 * 2) ^ ((row & 7) << 4);
            *reinterpret_cast<half8*>(AsB + byte) = hv;
        }
        __syncthreads();

        const int w = t >> 6, lane = t & 63;
        const int r0 = (w & 1) * 32, c0 = (w >> 1) * 64;
        const int lr = lane & 15;
        const int lk = (lane >> 4) * 8;

        f32x4 acc[2][4] = {};
        #pragma unroll
        for (int k0 = 0; k0 < 128; k0 += 32) {
            half8 af[2], bf[4];
            #pragma unroll
            for (int mi = 0; mi < 2; ++mi) {
                int row = r0 + mi * 16 + lr;
                int byte = (row * 256 + (k0 + lk) * 2) ^ ((row & 7) << 4);
                af[mi] = *reinterpret_cast<const half8*>(AsB + byte);
            }
            #pragma unroll
            for (int ni = 0; ni < 4; ++ni) {
                int col = c0 + ni * 16 + lr;
                bf[ni] = *reinterpret_cast<const half8*>(&Wr[(size_t)col * 128 + k0 + lk]);
            }
            #pragma unroll
            for (int mi = 0; mi < 2; ++mi)
                #pragma unroll
                for (int ni = 0; ni < 4; ++ni)
                    acc[mi][ni] = __builtin_amdgcn_mfma_f32_16x16x32_f16(af[mi], bf[ni],
                                                                         acc[mi][ni], 0, 0, 0);
        }
        __syncthreads();
        unsigned char* ht = reinterpret_cast<unsigned char*>(AsB);  // 64x128 bytes
        #pragma unroll
        for (int ni = 0; ni < 4; ++ni) {
            int col = c0 + ni * 16 + lr;
            float bb = bias[col];
            #pragma unroll
            for (int mi = 0; mi < 2; ++mi) {
                #pragma unroll
                for (int j = 0; j < 4; ++j) {
                    int row = r0 + mi * 16 + (lane >> 4) * 4 + j;
                    float y = fmaxf(acc[mi][ni][j] + bb, 0.f);
                    int e = __builtin_amdgcn_cvt_pk_fp8_f32(y, 0.f, 0, false);
                    ht[row * 128 + col] = (unsigned char)e;
                }
            }
        }
        __syncthreads();
        {
            int row = t >> 2, cb = (t & 3) * 32;
            int grow = n0 + row;
            if (grow < M) {
                const int4* p = reinterpret_cast<const int4*>(ht + row * 128 + cb);
                int4 a = p[0], b = p[1];
                int4* q = reinterpret_cast<int4*>(Hr + (size_t)grow * 128 + cb);
                q[0] = a; q[1] = b;
            }
        }
    }
}

// per 512-node bucket: self-allocated window, LDS hist -> offc{beg,cnt},
// scatter records direct to ushort sorted[] (window is L2-local)
__global__ __launch_bounds__(256) void csr2_k(const int* __restrict__ staging,
                                              const int* __restrict__ bcur,
                                              int* __restrict__ gcur,
                                              int2* __restrict__ offc,
                                              unsigned short* __restrict__ sorted,
                                              int nb1, int N) {
    const int r = blockIdx.y;
    const int b = blockIdx.x;
    const int gi = r * nb1 + b;
    const int sz = min(bcur[(size_t)gi * 16], BCAP1);
    const int* stg = staging + (size_t)gi * BCAP1;
    const int nbase = b * BN1;
    const int t = threadIdx.x;
    const int lane = t & 63, wid = t >> 6;

    __shared__ int hist[BN1];
    __shared__ int cur[BN1];
    __shared__ int wsum[4];
    __shared__ int base_s;

    if (t == 0) base_s = atomicAdd(gcur, sz);
    hist[t] = 0;
    hist[t + 256] = 0;
    __syncthreads();
    {
        const int sz4 = sz >> 2;
        const int4* s4 = reinterpret_cast<const int4*>(stg);
        for (int i = t; i < sz4; i += 256) {
            int4 v = s4[i];
            atomicAdd(&hist[((unsigned)v.x) >> 16], 1);
            atomicAdd(&hist[((unsigned)v.y) >> 16], 1);
            atomicAdd(&hist[((unsigned)v.z) >> 16], 1);
            atomicAdd(&hist[((unsigned)v.w) >> 16], 1);
        }
        for (int i = sz4 * 4 + t; i < sz; i += 256)
            atomicAdd(&hist[((unsigned)stg[i]) >> 16], 1);
    }
    __syncthreads();
    const int base = base_s;
    int v0 = hist[2 * t], v1 = hist[2 * t + 1];
    int ps = v0 + v1;
    int incl = ps;
    #pragma unroll
    for (int d = 1; d < 64; d <<= 1) {
        int x = __shfl_up(incl, d);
        if (lane >= d) incl += x;
    }
    if (lane == 63) wsum[wid] = incl;
    __syncthreads();
    if (t == 0) {
        int a = 0;
        #pragma unroll
        for (int i = 0; i < 4; ++i) { int x = wsum[i]; wsum[i] = a; a += x; }
    }
    __syncthreads();
    int e0 = wsum[wid] + incl - ps;
    cur[2 * t] = e0;
    cur[2 * t + 1] = e0 + v0;
    {
        int n0 = nbase + 2 * t;
        if (n0 < N) offc[(size_t)r * N + n0] = make_int2(base + e0, v0);
        if (n0 + 1 < N) offc[(size_t)r * N + n0 + 1] = make_int2(base + e0 + v0, v1);
    }
    __syncthreads();
    {
        const int sz4 = sz >> 2;
        const int4* s4 = reinterpret_cast<const int4*>(stg);
        for (int i = t; i < sz4; i += 256) {
            int4 v = s4[i];
            int p;
            p = atomicAdd(&cur[((unsigned)v.x) >> 16], 1);
            sorted[base + p] = (unsigned short)(v.x & 0xFFFF);
            p = atomicAdd(&cur[((unsigned)v.y) >> 16], 1);
            sorted[base + p] = (unsigned short)(v.y & 0xFFFF);
            p = atomicAdd(&cur[((unsigned)v.z) >> 16], 1);
            sorted[base + p] = (unsigned short)(v.z & 0xFFFF);
            p = atomicAdd(&cur[((unsigned)v.w) >> 16], 1);
            sorted[base + p] = (unsigned short)(v.w & 0xFFFF);
        }
        for (int i = sz4 * 4 + t; i < sz; i += 256) {
            int rec = stg[i];
            int p = atomicAdd(&cur[((unsigned)rec) >> 16], 1);
            sorted[base + p] = (unsigned short)(rec & 0xFFFF);
        }
    }
}

// one wave per node: gather+mean all 4 relations. 16 lanes x 8B fp8 per edge,
// 16 edges per main step (4 bpermute ids, 4 row loads in flight), id-block
// prefetch, packed f32x2 accumulation. Fused attention combine -> comb fp16.
__global__ __launch_bounds__(256) void gather_attn_k(const unsigned char* __restrict__ H8,
                                                     const float* __restrict__ xn,
                                                     const float* __restrict__ u,
                                                     const int2* __restrict__ offc,
                                                     const unsigned short* __restrict__ sorted,
                                                     __half* __restrict__ comb, int N) {
    const int node = blockIdx.x * 4 + (threadIdx.x >> 6);
    if (node >= N) return;
    const int lane = threadIdx.x & 63;
    const int q = lane >> 4;      // quadrant: edge slot
    const int c = lane & 15;      // col group: fp8 bytes [c*8, c*8+8)

    float2 x2 = *reinterpret_cast<const float2*>(&xn[(size_t)node * 128 + lane * 2]);
    float2 ux = *reinterpret_cast<const float2*>(&u[128 + lane * 2]);
    float px = x2.x * ux.x + x2.y * ux.y;
    #pragma unroll
    for (int m = 1; m < 64; m <<= 1) px += __shfl_xor(px, m);

    float4 ua0 = reinterpret_cast<const float4*>(u)[c * 2];
    float4 ua1 = reinterpret_cast<const float4*>(u)[c * 2 + 1];

    float a[4][8];
    float invd[4], pr[4];
    #pragma unroll
    for (int r = 0; r < 4; ++r) {
        const int2 oc = offc[(size_t)r * N + node];
        const int beg = oc.x, cnt = oc.y;
        const unsigned char* hr = H8 + (size_t)r * N * 128;
        const unsigned short* sl = sorted + beg;
        f32x2 s01 = {0.f, 0.f}, s23 = {0.f, 0.f}, s45 = {0.f, 0.f}, s67 = {0.f, 0.f};
        int my = (lane < cnt) ? (int)sl[lane] : 0;
        for (int j0 = 0; j0 < cnt; j0 += 64) {
            const int m = min(64, cnt - j0);
            int my_next = (j0 + 64 + lane < cnt) ? (int)sl[j0 + 64 + lane] : 0;  // prefetch
            int j = 0;
            for (; j + 16 <= m; j += 16) {         // 4 row loads in flight
                int tg0 = __shfl(my, j + q);
                int tg1 = __shfl(my, j + q + 4);
                int tg2 = __shfl(my, j + q + 8);
                int tg3 = __shfl(my, j + q + 12);
                uint2 raw0 = reinterpret_cast<const uint2*>(hr + (size_t)tg0 * 128)[c];
                uint2 raw1 = reinterpret_cast<const uint2*>(hr + (size_t)tg1 * 128)[c];
                uint2 raw2 = reinterpret_cast<const uint2*>(hr + (size_t)tg2 * 128)[c];
                uint2 raw3 = reinterpret_cast<const uint2*>(hr + (size_t)tg3 * 128)[c];
                s01 += __builtin_amdgcn_cvt_pk_f32_fp8((int)raw0.x, false);
                s23 += __builtin_amdgcn_cvt_pk_f32_fp8((int)raw0.x, true);
                s45 += __builtin_amdgcn_cvt_pk_f32_fp8((int)raw0.y, false);
                s67 += __builtin_amdgcn_cvt_pk_f32_fp8((int)raw0.y, true);
                s01 += __builtin_amdgcn_cvt_pk_f32_fp8((int)raw1.x, false);
                s23 += __builtin_amdgcn_cvt_pk_f32_fp8((int)raw1.x, true);
                s45 += __builtin_amdgcn_cvt_pk_f32_fp8((int)raw1.y, false);
                s67 += __builtin_amdgcn_cvt_pk_f32_fp8((int)raw1.y, true);
                s01 += __builtin_amdgcn_cvt_pk_f32_fp8((int)raw2.x, false);
                s23 += __builtin_amdgcn_cvt_pk_f32_fp8((int)raw2.x, true);
                s45 += __builtin_amdgcn_cvt_pk_f32_fp8((int)raw2.y, false);
                s67 += __builtin_amdgcn_cvt_pk_f32_fp8((int)raw2.y, true);
                s01 += __builtin_amdgcn_cvt_pk_f32_fp8((int)raw3.x, false);
                s23 += __builtin_amdgcn_cvt_pk_f32_fp8((int)raw3.x, true);
                s45 += __builtin_amdgcn_cvt_pk_f32_fp8((int)raw3.y, false);
                s67 += __builtin_amdgcn_cvt_pk_f32_fp8((int)raw3.y, true);
            }
            for (; j + 8 <= m; j += 8) {
                int tg0 = __shfl(my, j + q);
                int tg1 = __shfl(my, j + q + 4);
                uint2 raw0 = reinterpret_cast<const uint2*>(hr + (size_t)tg0 * 128)[c];
                uint2 raw1 = reinterpret_cast<const uint2*>(hr + (size_t)tg1 * 128)[c];
                s01 += __builtin_amdgcn_cvt_pk_f32_fp8((int)raw0.x, false);
                s23 += __builtin_amdgcn_cvt_pk_f32_fp8((int)raw0.x, true);
                s45 += __builtin_amdgcn_cvt_pk_f32_fp8((int)raw0.y, false);
                s67 += __builtin_amdgcn_cvt_pk_f32_fp8((int)raw0.y, true);
                s01 += __builtin_amdgcn_cvt_pk_f32_fp8((int)raw1.x, false);
                s23 += __builtin_amdgcn_cvt_pk_f32_fp8((int)raw1.x, true);
                s45 += __builtin_amdgcn_cvt_pk_f32_fp8((int)raw1.y, false);
                s67 += __builtin_amdgcn_cvt_pk_f32_fp8((int)raw1.y, true);
            }
            for (; j < m; j += 4) {                // masked tail (<8 edges)
                int jj = j + q;
                int tg = __shfl(my, min(jj, m - 1));
                if (jj < m) {
                    uint2 raw = reinterpret_cast<const uint2*>(hr + (size_t)tg * 128)[c];
                    s01 += __builtin_amdgcn_cvt_pk_f32_fp8((int)raw.x, false);
                    s23 += __builtin_amdgcn_cvt_pk_f32_fp8((int)raw.x, true);
                    s45 += __builtin_amdgcn_cvt_pk_f32_fp8((int)raw.y, false);
                    s67 += __builtin_amdgcn_cvt_pk_f32_fp8((int)raw.y, true);
                }
            }
            my = my_next;
        }
        float s[8] = {s01[0], s01[1], s23[0], s23[1], s45[0], s45[1], s67[0], s67[1]};
        #pragma unroll
        for (int k = 0; k < 8; ++k) {
            s[k] += __shfl_xor(s[k], 16);
            s[k] += __shfl_xor(s[k], 32);
        }
        float dp = s[0] * ua0.x + s[1] * ua0.y + s[2] * ua0.z + s[3] * ua0.w
                 + s[4] * ua1.x + s[5] * ua1.y + s[6] * ua1.z + s[7] * ua1.w;
        #pragma unroll
        for (int m = 1; m < 16; m <<= 1) dp += __shfl_xor(dp, m);
        pr[r] = dp;
        invd[r] = 1.0f / fmaxf((float)cnt, 1.0f);
        #pragma unroll
        for (int k = 0; k < 8; ++k) a[r][k] = s[k];
    }
    float wgt[4], denom = 0.f;
    #pragma unroll
    for (int r = 0; r < 4; ++r) {
        float sc = pr[r] * invd[r] + px;
        float z = (sc > 0.f) ? sc : 0.01f * sc;   // leaky_relu 0.01
        wgt[r] = expf(z);
        denom += wgt[r];
    }
    float cf[4];
    #pragma unroll
    for (int r = 0; r < 4; ++r) cf[r] = (wgt[r] / denom) * invd[r];
    if (q == 0) {
        half8 o;
        #pragma unroll
        for (int k = 0; k < 8; ++k)
            o[k] = (_Float16)(cf[0] * a[0][k] + cf[1] * a[1][k] +
                              cf[2] * a[2][k] + cf[3] * a[3][k]);
        *reinterpret_cast<half8*>(&comb[(size_t)node * 128 + c * 8]) = o;
    }
}

// y = relu([xn|comb][M,256] @ Wl + bl); out = y / max(||y||2, 1e-12). fp16 MFMA.
__global__ __launch_bounds__(256) void gemm_out_k(const float* __restrict__ Xn,
                                                  const __half* __restrict__ Cb,
                                                  const __half* __restrict__ Wlt,
                                                  const float* __restrict__ bias,
                                                  float* __restrict__ out, int M) {
    __shared__ __half As[64 * 128];
    __shared__ float rowss[64];
    const int t = threadIdx.x;
    const int n0 = blockIdx.x * 64;
    char* AsB = reinterpret_cast<char*>(As);
    if (t < 64) rowss[t] = 0.f;

    const int w = t >> 6, lane = t & 63;
    const int r0 = (w & 1) * 32, c0 = (w >> 1) * 64;
    const int lr = lane & 15;
    const int lk = (lane >> 4) * 8;

    f32x4 acc[2][4] = {};
    #pragma unroll
    for (int p = 0; p < 2; ++p) {
        if (p == 0) {
            for (int s = t; s < 1024; s += 256) {
                int row = s >> 4, c8 = (s & 15) << 3;
                int grow = n0 + row;
                float4 v0 = make_float4(0.f, 0.f, 0.f, 0.f), v1 = v0;
                if (grow < M) {
                    v0 = *reinterpret_cast<const float4*>(&Xn[(size_t)grow * 128 + c8]);
                    v1 = *reinterpret_cast<const float4*>(&Xn[(size_t)grow * 128 + c8 + 4]);
                }
                half8 hv;
                hv[0] = (_Float16)v0.x; hv[1] = (_Float16)v0.y;
                hv[2] = (_Float16)v0.z; hv[3] = (_Float16)v0.w;
                hv[4] = (_Float16)v1.x; hv[5] = (_Float16)v1.y;
                hv[6] = (_Float16)v1.z; hv[7] = (_Float16)v1.w;
                int byte = (row * 256 + c8 * 2) ^ ((row & 7) << 4);
                *reinterpret_cast<half8*>(AsB + byte) = hv;
            }
        } else {
            for (int s = t; s < 1024; s += 256) {
                int row = s >> 4, c8 = (s & 15) << 3;
                int grow = n0 + row;
                half8 hv = {};
                if (grow < M) hv = *reinterpret_cast<const half8*>(&Cb[(size_t)grow * 128 + c8]);
                int byte = (row * 256 + c8 * 2) ^ ((row & 7) << 4);
                *reinterpret_cast<half8*>(AsB + byte) = hv;
            }
        }
        __syncthreads();
        #pragma unroll
        for (int k0 = 0; k0 < 128; k0 += 32) {
            half8 af[2], bf[4];
            #pragma unroll
            for (int mi = 0; mi < 2; ++mi) {
                int row = r0 + mi * 16 + lr;
                int byte = (row * 256 + (k0 + lk) * 2) ^ ((row & 7) << 4);
                af[mi] = *reinterpret_cast<const half8*>(AsB + byte);
            }
            #pragma unroll
            for (int ni = 0; ni < 4; ++ni) {
                int col = c0 + ni * 16 + lr;
                bf[ni] = *reinterpret_cast<const half8*>(&Wlt[(size_t)col * 256 + p * 128 + k0 + lk]);
            }
            #pragma unroll
            for (int mi = 0; mi < 2; ++mi)
                #pragma unroll
                for (int ni = 0; ni < 4; ++ni)
                    acc[mi][ni] = __builtin_amdgcn_mfma_f32_16x16x32_f16(af[mi], bf[ni],
                                                                         acc[mi][ni], 0, 0, 0);
        }
        __syncthreads();
    }
    float bbv[4];
    #pragma unroll
    for (int ni = 0; ni < 4; ++ni) bbv[ni] = bias[c0 + ni * 16 + lr];
    #pragma unroll
    for (int mi = 0; mi < 2; ++mi) {
        #pragma unroll
        for (int j = 0; j < 4; ++j) {
            int row_l = r0 + mi * 16 + (lane >> 4) * 4 + j;
            float ss = 0.f;
            #pragma unroll
            for (int ni = 0; ni < 4; ++ni) {
                float y = fmaxf(acc[mi][ni][j] + bbv[ni], 0.f);
                ss += y * y;
            }
            ss += __shfl_xor(ss, 1); ss += __shfl_xor(ss, 2);
            ss += __shfl_xor(ss, 4); ss += __shfl_xor(ss, 8);
            if (lr == 0) atomicAdd(&rowss[row_l], ss);
        }
    }
    __syncthreads();
    #pragma unroll
    for (int mi = 0; mi < 2; ++mi) {
        #pragma unroll
        for (int j = 0; j < 4; ++j) {
            int row_l = r0 + mi * 16 + (lane >> 4) * 4 + j;
            int grow = n0 + row_l;
            if (grow < M) {
                float inv = 1.0f / fmaxf(sqrtf(rowss[row_l]), 1e-12f);
                #pragma unroll
                for (int ni = 0; ni < 4; ++ni) {
                    float y = fmaxf(acc[mi][ni][j] + bbv[ni], 0.f);
                    out[(size_t)grow * 128 + c0 + ni * 16 + lr] = y * inv;
                }
            }
        }
    }
}

extern "C" void kernel_launch(void* const* d_in, const int* in_sizes, int n_in,
                              void* d_out, int out_size, void* d_ws, size_t ws_size,
                              hipStream_t stream) {
    FP4 X  = {{(const float*)d_in[0], (const float*)d_in[2],
               (const float*)d_in[4], (const float*)d_in[6]}};
    IP4 ED = {{(const int*)d_in[1], (const int*)d_in[3],
               (const int*)d_in[5], (const int*)d_in[7]}};
    const float* xn = (const float*)d_in[8];
    FP4 Wm = {{(const float*)d_in[10], (const float*)d_in[12],
               (const float*)d_in[14], (const float*)d_in[16]}};
    FP4 Bv = {{(const float*)d_in[11], (const float*)d_in[13],
               (const float*)d_in[15], (const float*)d_in[17]}};
    const float* u  = (const float*)d_in[18];
    const float* Wl = (const float*)d_in[19];
    const float* bl = (const float*)d_in[20];
    float* out = (float*)d_out;

    const int N = in_sizes[8] / 128;
    int E[4];
    for (int r = 0; r < 4; ++r) E[r] = in_sizes[1 + 2 * r] / 2;
    const int4 Ev = make_int4(E[0], E[1], E[2], E[3]);
    const int nb1 = (N + BN1 - 1) / BN1;
    int maxE = 0;
    for (int r = 0; r < 4; ++r) maxE = (E[r] > maxE) ? E[r] : maxE;

    // ws layout
    unsigned char* h8 = (unsigned char*)d_ws;                    // 4*N*128 bytes
    char*  ubase   = (char*)(h8 + (size_t)4 * N * 128);
    int*   staging = (int*)ubase;                                // 4*nb1*BCAP1 ints
    __half* comb   = (__half*)ubase;                             // N*128 halfs (alias)
    size_t usz = (size_t)4 * nb1 * BCAP1 * sizeof(int);
    size_t csz = (size_t)N * 128 * sizeof(__half);
    char*  after   = ubase + (usz > csz ? usz : csz);
    __half* Wt     = (__half*)after;                             // 4*16384 halfs
    __half* Wlt    = Wt + (size_t)4 * 16384;                     // 128*256 halfs
    int2* offc   = (int2*)(Wlt + (size_t)128 * 256);             // 4*N int2
    int* bcur    = (int*)(offc + (size_t)4 * N);                 // 4*nb1*16
    int* gcur    = bcur + (size_t)4 * nb1 * 16;                  // 16 (pad)
    unsigned short* sorted = (unsigned short*)(gcur + 16);       // sumE ushorts

    const int gb = (N + 63) / 64;
    const int binb = (maxE + BLK_E - 1) / BLK_E;

    prep0_k<<<448, 256, 0, stream>>>(Wm, Wl, Wt, Wlt, bcur, 4 * nb1 * 16 + 16);
    binGemm_k<<<4 * binb + 4 * gb, 256, 0, stream>>>(ED, Ev, bcur, staging, nb1, binb,
                                                     X, Wt, Bv, h8, N, gb);
    csr2_k<<<dim3(nb1, 4), 256, 0, stream>>>(staging, bcur, gcur, offc, sorted, nb1, N);
    gather_attn_k<<<(N + 3) / 4, 256, 0, stream>>>(h8, xn, u, offc, sorted, comb, N);
    gemm_out_k<<<gb, 256, 0, stream>>>(xn, comb, Wlt, bl, out, N);
}

// Round 15
// 302.425 us; speedup vs baseline: 1.7063x; 1.0176x over previous
//
#include <hip/hip_runtime.h>
#include <hip/hip_fp16.h>
#include <cstddef>

// ---------------------------------------------------------------------------
// Het_Agg: 4-relation GNN aggregation + attention combine + linear + L2 norm
// fp32 in/out; h staged as fp8 e4m3 (HW cvt), comb staged fp16.
// CSR build: counting sort with 512-node buckets.
//   binGemm (fused): block-aggregated binning into per-bucket runs  ||  h-gemm
//     (bin pass-1 uses 4-way replicated LDS hist, one replica per wave)
//   csr2: per bucket: self-allocated window (global cursor), LDS hist(512)
//         -> offc{beg,cnt}, scatter records direct to ushort sorted[]
// gather: one wave/node, 16 lanes x 8B fp8 per edge row, 8 edges/step
// (bpermute broadcast + id-block prefetch), packed f32x2 accumulation.
// [R14 lesson: deeper unroll costs VGPR/occupancy and LOSES at the
//  outstanding-miss limit; 8-edge/48-VGPR/51%-occ is the gather optimum.]
// ---------------------------------------------------------------------------

#define BN1       512    // nodes per bucket
#define BN1_SHIFT 9
#define BCAP1     20480  // mean 16384 @ E=1.6M,N=50K; +32 sigma margin
#define NB1MAX    128    // max buckets/relation (N <= 65536)
#define BLK_E     16384  // edges per binning block

struct IP4 { const int* p[4]; };
struct FP4 { const float* p[4]; };

typedef _Float16 half8 __attribute__((ext_vector_type(8)));
typedef float f32x4 __attribute__((ext_vector_type(4)));
typedef float f32x2 __attribute__((ext_vector_type(2)));

// prep: Wt[r][c][k]=fp16(W_r[k][c]); Wlt[c][k]=fp16(Wl[k][c]); zero bcur+gcur
__global__ __launch_bounds__(256) void prep0_k(FP4 Wm, const float* __restrict__ Wl,
                                               __half* __restrict__ Wt,
                                               __half* __restrict__ Wlt,
                                               int* __restrict__ bcur, int nzero) {
    const int b = blockIdx.x, t = threadIdx.x;
    if (b < 256) {
        int r = b >> 6;
        int i = (b & 63) * 256 + t;           // 0..16383
        int k = i & 127, c = i >> 7;
        Wt[(size_t)r * 16384 + c * 128 + k] = __float2half(Wm.p[r][(size_t)k * 128 + c]);
    } else if (b < 384) {
        int i = (b - 256) * 256 + t;          // 0..32767
        int k = i & 255, c = i >> 8;
        Wlt[(size_t)c * 256 + k] = __float2half(Wl[(size_t)k * 128 + c]);
    } else {
        for (int i = (b - 384) * 256 + t; i < nzero; i += 64 * 256) bcur[i] = 0;
    }
}

// FUSED: 512-node-bucket binning (x < 4*binb)  ||  h = relu(xW+b) -> fp8 gemm
__global__ __launch_bounds__(256) void binGemm_k(IP4 ed, int4 Ev, int* __restrict__ bcur,
                                                 int* __restrict__ staging, int nb1, int binb,
                                                 FP4 X, const __half* __restrict__ Wt,
                                                 FP4 Bv, unsigned char* __restrict__ H8,
                                                 int M, int gb) {
    __shared__ int ldsu[4096];   // 16 KB union: bin{hist x4, curs} / gemm{As}
    const int t = threadIdx.x;
    const int x = blockIdx.x;

    if (x < 4 * binb) {
        // ------------------------- bin role -------------------------
        const int r = x / binb;
        const int bx = x - r * binb;
        const int E = (r == 0) ? Ev.x : (r == 1) ? Ev.y : (r == 2) ? Ev.z : Ev.w;
        const int e0 = bx * BLK_E;
        if (e0 >= E) return;
        const int e1 = min(e0 + BLK_E, E);
        const int* es = ed.p[r];
        const int* et = es + E;
        int* bc = bcur + (size_t)r * nb1 * 16;
        int* stg = staging + (size_t)r * nb1 * BCAP1;
        int* hist = ldsu;                    // 4 replicas x NB1MAX
        int* curs = ldsu + 4 * NB1MAX;
        int* hw = hist + (t >> 6) * NB1MAX;  // this wave's replica

        for (int b = t; b < 4 * NB1MAX; b += 256) hist[b] = 0;
        __syncthreads();
        {
            const int n = e1 - e0;
            const int n4 = n >> 2;
            const int4* s4 = reinterpret_cast<const int4*>(es + e0);
            for (int i = t; i < n4; i += 256) {
                int4 s = s4[i];
                atomicAdd(&hw[s.x >> BN1_SHIFT], 1);
                atomicAdd(&hw[s.y >> BN1_SHIFT], 1);
                atomicAdd(&hw[s.z >> BN1_SHIFT], 1);
                atomicAdd(&hw[s.w >> BN1_SHIFT], 1);
            }
            for (int i = e0 + n4 * 4 + t; i < e1; i += 256)
                atomicAdd(&hw[es[i] >> BN1_SHIFT], 1);
        }
        __syncthreads();
        for (int b = t; b < nb1; b += 256) {
            int c = hist[b] + hist[NB1MAX + b] + hist[2 * NB1MAX + b] + hist[3 * NB1MAX + b];
            curs[b] = c ? atomicAdd(&bc[b * 16], c) : 0;
        }
        __syncthreads();
        {
            const int n = e1 - e0;
            const int n4 = n >> 2;
            const int4* s4 = reinterpret_cast<const int4*>(es + e0);
            const int4* t4 = reinterpret_cast<const int4*>(et + e0);
            for (int i = t; i < n4; i += 256) {
                int4 s = s4[i];
                int4 tg = t4[i];
                int b, p;
                b = s.x >> BN1_SHIFT; p = atomicAdd(&curs[b], 1);
                if (p < BCAP1) stg[(size_t)b * BCAP1 + p] = ((s.x & 511) << 16) | tg.x;
                b = s.y >> BN1_SHIFT; p = atomicAdd(&curs[b], 1);
                if (p < BCAP1) stg[(size_t)b * BCAP1 + p] = ((s.y & 511) << 16) | tg.y;
                b = s.z >> BN1_SHIFT; p = atomicAdd(&curs[b], 1);
                if (p < BCAP1) stg[(size_t)b * BCAP1 + p] = ((s.z & 511) << 16) | tg.z;
                b = s.w >> BN1_SHIFT; p = atomicAdd(&curs[b], 1);
                if (p < BCAP1) stg[(size_t)b * BCAP1 + p] = ((s.w & 511) << 16) | tg.w;
            }
            for (int i = e0 + n4 * 4 + t; i < e1; i += 256) {
                int s = es[i];
                int b = s >> BN1_SHIFT;
                int p = atomicAdd(&curs[b], 1);
                if (p < BCAP1) stg[(size_t)b * BCAP1 + p] = ((s & 511) << 16) | et[i];
            }
        }
    } else {
        // ------------------------- gemm role ------------------------
        const int g = x - 4 * binb;
        const int r = g / gb;
        const int bx = g - r * gb;
        const float* A = X.p[r];
        const __half* Wr = Wt + (size_t)r * 16384;
        const float* bias = Bv.p[r];
        unsigned char* Hr = H8 + (size_t)r * M * 128;
        const int n0 = bx * 64;
        char* AsB = reinterpret_cast<char*>(ldsu);

        for (int s = t; s < 1024; s += 256) {
            int row = s >> 4, c8 = (s & 15) << 3;
            int grow = n0 + row;
            float4 v0 = make_float4(0.f, 0.f, 0.f, 0.f), v1 = v0;
            if (grow < M) {
                v0 = *reinterpret_cast<const float4*>(&A[(size_t)grow * 128 + c8]);
                v1 = *reinterpret_cast<const float4*>(&A[(size_t)grow * 128 + c8 + 4]);
            }
            half8 hv;
            hv[0] = (_Float16)v0.x; hv[1] = (_Float16)v0.y;
            hv[2] = (_Float16)v0.z; hv[3] = (_Float16)v0.w;
            hv[4] = (_Float16)v1.x; hv[5] = (_Float16)v1.y;
            hv[6] = (_Float16)v1.z; hv[7] = (_Float16)v1.w;
            int byte = (row * 256 + c8 * 2) ^ ((row & 7) << 4);
            *reinterpret_cast<half8*>(AsB + byte) = hv;
        }
        __syncthreads();

        const int w = t >> 6, lane = t & 63;
        const int r0 = (w & 1) * 32, c0 = (w >> 1) * 64;
        const int lr = lane & 15;
        const int lk = (lane >> 4) * 8;

        f32x4 acc[2][4] = {};
        #pragma unroll
        for (int k0 = 0; k0 < 128; k0 += 32) {
            half8 af[2], bf[4];
            #pragma unroll
            for (int mi = 0; mi < 2; ++mi) {
                int row = r0 + mi * 16 + lr;
                int byte = (row * 256 + (k0 + lk) * 2) ^ ((row & 7) << 4);
                af[mi] = *reinterpret_cast<const half8*>(AsB + byte);
            }
            #pragma unroll
            for (int ni = 0; ni < 4; ++ni) {
                int col = c0 + ni * 16 + lr;
                bf[ni] = *reinterpret_cast<const half8*>(&Wr[(size_t)col * 128 + k0 + lk]);
            }
            #pragma unroll
            for (int mi = 0; mi < 2; ++mi)
                #pragma unroll
                for (int ni = 0; ni < 4; ++ni)
                    acc[mi][ni] = __builtin_amdgcn_mfma_f32_16x16x32_f16(af[mi], bf[ni],
                                                                         acc[mi][ni], 0, 0, 0);
        }
        __syncthreads();
        unsigned char* ht = reinterpret_cast<unsigned char*>(AsB);  // 64x128 bytes
        #pragma unroll
        for (int ni = 0; ni < 4; ++ni) {
            int col = c0 + ni * 16 + lr;
            float bb = bias[col];
            #pragma unroll
            for (int mi = 0; mi < 2; ++mi) {
                #pragma unroll
                for (int j = 0; j < 4; ++j) {
                    int row = r0 + mi * 16 + (lane >> 4) * 4 + j;
                    float y = fmaxf(acc[mi][ni][j] + bb, 0.f);
                    int e = __builtin_amdgcn_cvt_pk_fp8_f32(y, 0.f, 0, false);
                    ht[row * 128 + col] = (unsigned char)e;
                }
            }
        }
        __syncthreads();
        {
            int row = t >> 2, cb = (t & 3) * 32;
            int grow = n0 + row;
            if (grow < M) {
                const int4* p = reinterpret_cast<const int4*>(ht + row * 128 + cb);
                int4 a = p[0], b = p[1];
                int4* q = reinterpret_cast<int4*>(Hr + (size_t)grow * 128 + cb);
                q[0] = a; q[1] = b;
            }
        }
    }
}

// per 512-node bucket: self-allocated window, LDS hist -> offc{beg,cnt},
// scatter records direct to ushort sorted[] (window is L2-local)
__global__ __launch_bounds__(256) void csr2_k(const int* __restrict__ staging,
                                              const int* __restrict__ bcur,
                                              int* __restrict__ gcur,
                                              int2* __restrict__ offc,
                                              unsigned short* __restrict__ sorted,
                                              int nb1, int N) {
    const int r = blockIdx.y;
    const int b = blockIdx.x;
    const int gi = r * nb1 + b;
    const int sz = min(bcur[(size_t)gi * 16], BCAP1);
    const int* stg = staging + (size_t)gi * BCAP1;
    const int nbase = b * BN1;
    const int t = threadIdx.x;
    const int lane = t & 63, wid = t >> 6;

    __shared__ int hist[BN1];
    __shared__ int cur[BN1];
    __shared__ int wsum[4];
    __shared__ int base_s;

    if (t == 0) base_s = atomicAdd(gcur, sz);
    hist[t] = 0;
    hist[t + 256] = 0;
    __syncthreads();
    {
        const int sz4 = sz >> 2;
        const int4* s4 = reinterpret_cast<const int4*>(stg);
        for (int i = t; i < sz4; i += 256) {
            int4 v = s4[i];
            atomicAdd(&hist[((unsigned)v.x) >> 16], 1);
            atomicAdd(&hist[((unsigned)v.y) >> 16], 1);
            atomicAdd(&hist[((unsigned)v.z) >> 16], 1);
            atomicAdd(&hist[((unsigned)v.w) >> 16], 1);
        }
        for (int i = sz4 * 4 + t; i < sz; i += 256)
            atomicAdd(&hist[((unsigned)stg[i]) >> 16], 1);
    }
    __syncthreads();
    const int base = base_s;
    int v0 = hist[2 * t], v1 = hist[2 * t + 1];
    int ps = v0 + v1;
    int incl = ps;
    #pragma unroll
    for (int d = 1; d < 64; d <<= 1) {
        int x = __shfl_up(incl, d);
        if (lane >= d) incl += x;
    }
    if (lane == 63) wsum[wid] = incl;
    __syncthreads();
    if (t == 0) {
        int a = 0;
        #pragma unroll
        for (int i = 0; i < 4; ++i) { int x = wsum[i]; wsum[i] = a; a += x; }
    }
    __syncthreads();
    int e0 = wsum[wid] + incl - ps;
    cur[2 * t] = e0;
    cur[2 * t + 1] = e0 + v0;
    {
        int n0 = nbase + 2 * t;
        if (n0 < N) offc[(size_t)r * N + n0] = make_int2(base + e0, v0);
        if (n0 + 1 < N) offc[(size_t)r * N + n0 + 1] = make_int2(base + e0 + v0, v1);
    }
    __syncthreads();
    {
        const int sz4 = sz >> 2;
        const int4* s4 = reinterpret_cast<const int4*>(stg);
        for (int i = t; i < sz4; i += 256) {
            int4 v = s4[i];
            int p;
            p = atomicAdd(&cur[((unsigned)v.x) >> 16], 1);
            sorted[base + p] = (unsigned short)(v.x & 0xFFFF);
            p = atomicAdd(&cur[((unsigned)v.y) >> 16], 1);
            sorted[base + p] = (unsigned short)(v.y & 0xFFFF);
            p = atomicAdd(&cur[((unsigned)v.z) >> 16], 1);
            sorted[base + p] = (unsigned short)(v.z & 0xFFFF);
            p = atomicAdd(&cur[((unsigned)v.w) >> 16], 1);
            sorted[base + p] = (unsigned short)(v.w & 0xFFFF);
        }
        for (int i = sz4 * 4 + t; i < sz; i += 256) {
            int rec = stg[i];
            int p = atomicAdd(&cur[((unsigned)rec) >> 16], 1);
            sorted[base + p] = (unsigned short)(rec & 0xFFFF);
        }
    }
}

// one wave per node: gather+mean all 4 relations. 16 lanes x 8B fp8 per edge,
// 8 edges per wave step (bpermute broadcast), id-block prefetch, packed f32x2.
__global__ __launch_bounds__(256) void gather_attn_k(const unsigned char* __restrict__ H8,
                                                     const float* __restrict__ xn,
                                                     const float* __restrict__ u,
                                                     const int2* __restrict__ offc,
                                                     const unsigned short* __restrict__ sorted,
                                                     __half* __restrict__ comb, int N) {
    const int node = blockIdx.x * 4 + (threadIdx.x >> 6);
    if (node >= N) return;
    const int lane = threadIdx.x & 63;
    const int q = lane >> 4;      // quadrant: edge slot
    const int c = lane & 15;      // col group: fp8 bytes [c*8, c*8+8)

    float2 x2 = *reinterpret_cast<const float2*>(&xn[(size_t)node * 128 + lane * 2]);
    float2 ux = *reinterpret_cast<const float2*>(&u[128 + lane * 2]);
    float px = x2.x * ux.x + x2.y * ux.y;
    #pragma unroll
    for (int m = 1; m < 64; m <<= 1) px += __shfl_xor(px, m);

    float4 ua0 = reinterpret_cast<const float4*>(u)[c * 2];
    float4 ua1 = reinterpret_cast<const float4*>(u)[c * 2 + 1];

    float a[4][8];
    float invd[4], pr[4];
    #pragma unroll
    for (int r = 0; r < 4; ++r) {
        const int2 oc = offc[(size_t)r * N + node];
        const int beg = oc.x, cnt = oc.y;
        const unsigned char* hr = H8 + (size_t)r * N * 128;
        const unsigned short* sl = sorted + beg;
        f32x2 s01 = {0.f, 0.f}, s23 = {0.f, 0.f}, s45 = {0.f, 0.f}, s67 = {0.f, 0.f};
        int my = (lane < cnt) ? (int)sl[lane] : 0;
        for (int j0 = 0; j0 < cnt; j0 += 64) {
            const int m = min(64, cnt - j0);
            int my_next = (j0 + 64 + lane < cnt) ? (int)sl[j0 + 64 + lane] : 0;  // prefetch
            int j = 0;
            for (; j + 8 <= m; j += 8) {           // branch-free: q+4 <= 7 < 8
                int tg0 = __shfl(my, j + q);
                int tg1 = __shfl(my, j + q + 4);
                uint2 raw0 = reinterpret_cast<const uint2*>(hr + (size_t)tg0 * 128)[c];
                uint2 raw1 = reinterpret_cast<const uint2*>(hr + (size_t)tg1 * 128)[c];
                s01 += __builtin_amdgcn_cvt_pk_f32_fp8((int)raw0.x, false);
                s23 += __builtin_amdgcn_cvt_pk_f32_fp8((int)raw0.x, true);
                s45 += __builtin_amdgcn_cvt_pk_f32_fp8((int)raw0.y, false);
                s67 += __builtin_amdgcn_cvt_pk_f32_fp8((int)raw0.y, true);
                s01 += __builtin_amdgcn_cvt_pk_f32_fp8((int)raw1.x, false);
                s23 += __builtin_amdgcn_cvt_pk_f32_fp8((int)raw1.x, true);
                s45 += __builtin_amdgcn_cvt_pk_f32_fp8((int)raw1.y, false);
                s67 += __builtin_amdgcn_cvt_pk_f32_fp8((int)raw1.y, true);
            }
            for (; j < m; j += 4) {                // masked tail (<8 edges)
                int jj = j + q;
                int tg = __shfl(my, min(jj, m - 1));
                if (jj < m) {
                    uint2 raw = reinterpret_cast<const uint2*>(hr + (size_t)tg * 128)[c];
                    s01 += __builtin_amdgcn_cvt_pk_f32_fp8((int)raw.x, false);
                    s23 += __builtin_amdgcn_cvt_pk_f32_fp8((int)raw.x, true);
                    s45 += __builtin_amdgcn_cvt_pk_f32_fp8((int)raw.y, false);
                    s67 += __builtin_amdgcn_cvt_pk_f32_fp8((int)raw.y, true);
                }
            }
            my = my_next;
        }
        float s[8] = {s01[0], s01[1], s23[0], s23[1], s45[0], s45[1], s67[0], s67[1]};
        #pragma unroll
        for (int k = 0; k < 8; ++k) {
            s[k] += __shfl_xor(s[k], 16);
            s[k] += __shfl_xor(s[k], 32);
        }
        float dp = s[0] * ua0.x + s[1] * ua0.y + s[2] * ua0.z + s[3] * ua0.w
                 + s[4] * ua1.x + s[5] * ua1.y + s[6] * ua1.z + s[7] * ua1.w;
        #pragma unroll
        for (int m = 1; m < 16; m <<= 1) dp += __shfl_xor(dp, m);
        pr[r] = dp;
        invd[r] = 1.0f / fmaxf((float)cnt, 1.0f);
        #pragma unroll
        for (int k = 0; k < 8; ++k) a[r][k] = s[k];
    }
    float wgt[4], denom = 0.f;
    #pragma unroll
    for (int r = 0; r < 4; ++r) {
        float sc = pr[r] * invd[r] + px;
        float z = (sc > 0.f) ? sc : 0.01f * sc;   // leaky_relu 0.01
        wgt[r] = expf(z);
        denom += wgt[r];
    }
    float cf[4];
    #pragma unroll
    for (int r = 0; r < 4; ++r) cf[r] = (wgt[r] / denom) * invd[r];
    if (q == 0) {
        half8 o;
        #pragma unroll
        for (int k = 0; k < 8; ++k)
            o[k] = (_Float16)(cf[0] * a[0][k] + cf[1] * a[1][k] +
                              cf[2] * a[2][k] + cf[3] * a[3][k]);
        *reinterpret_cast<half8*>(&comb[(size_t)node * 128 + c * 8]) = o;
    }
}

// y = relu([xn|comb][M,256] @ Wl + bl); out = y / max(||y||2, 1e-12). fp16 MFMA.
__global__ __launch_bounds__(256) void gemm_out_k(const float* __restrict__ Xn,
                                                  const __half* __restrict__ Cb,
                                                  const __half* __restrict__ Wlt,
                                                  const float* __restrict__ bias,
                                                  float* __restrict__ out, int M) {
    __shared__ __half As[64 * 128];
    __shared__ float rowss[64];
    const int t = threadIdx.x;
    const int n0 = blockIdx.x * 64;
    char* AsB = reinterpret_cast<char*>(As);
    if (t < 64) rowss[t] = 0.f;

    const int w = t >> 6, lane = t & 63;
    const int r0 = (w & 1) * 32, c0 = (w >> 1) * 64;
    const int lr = lane & 15;
    const int lk = (lane >> 4) * 8;

    f32x4 acc[2][4] = {};
    #pragma unroll
    for (int p = 0; p < 2; ++p) {
        if (p == 0) {
            for (int s = t; s < 1024; s += 256) {
                int row = s >> 4, c8 = (s & 15) << 3;
                int grow = n0 + row;
                float4 v0 = make_float4(0.f, 0.f, 0.f, 0.f), v1 = v0;
                if (grow < M) {
                    v0 = *reinterpret_cast<const float4*>(&Xn[(size_t)grow * 128 + c8]);
                    v1 = *reinterpret_cast<const float4*>(&Xn[(size_t)grow * 128 + c8 + 4]);
                }
                half8 hv;
                hv[0] = (_Float16)v0.x; hv[1] = (_Float16)v0.y;
                hv[2] = (_Float16)v0.z; hv[3] = (_Float16)v0.w;
                hv[4] = (_Float16)v1.x; hv[5] = (_Float16)v1.y;
                hv[6] = (_Float16)v1.z; hv[7] = (_Float16)v1.w;
                int byte = (row * 256 + c8 * 2) ^ ((row & 7) << 4);
                *reinterpret_cast<half8*>(AsB + byte) = hv;
            }
        } else {
            for (int s = t; s < 1024; s += 256) {
                int row = s >> 4, c8 = (s & 15) << 3;
                int grow = n0 + row;
                half8 hv = {};
                if (grow < M) hv = *reinterpret_cast<const half8*>(&Cb[(size_t)grow * 128 + c8]);
                int byte = (row * 256 + c8 * 2) ^ ((row & 7) << 4);
                *reinterpret_cast<half8*>(AsB + byte) = hv;
            }
        }
        __syncthreads();
        #pragma unroll
        for (int k0 = 0; k0 < 128; k0 += 32) {
            half8 af[2], bf[4];
            #pragma unroll
            for (int mi = 0; mi < 2; ++mi) {
                int row = r0 + mi * 16 + lr;
                int byte = (row * 256 + (k0 + lk) * 2) ^ ((row & 7) << 4);
                af[mi] = *reinterpret_cast<const half8*>(AsB + byte);
            }
            #pragma unroll
            for (int ni = 0; ni < 4; ++ni) {
                int col = c0 + ni * 16 + lr;
                bf[ni] = *reinterpret_cast<const half8*>(&Wlt[(size_t)col * 256 + p * 128 + k0 + lk]);
            }
            #pragma unroll
            for (int mi = 0; mi < 2; ++mi)
                #pragma unroll
                for (int ni = 0; ni < 4; ++ni)
                    acc[mi][ni] = __builtin_amdgcn_mfma_f32_16x16x32_f16(af[mi], bf[ni],
                                                                         acc[mi][ni], 0, 0, 0);
        }
        __syncthreads();
    }
    float bbv[4];
    #pragma unroll
    for (int ni = 0; ni < 4; ++ni) bbv[ni] = bias[c0 + ni * 16 + lr];
    #pragma unroll
    for (int mi = 0; mi < 2; ++mi) {
        #pragma unroll
        for (int j = 0; j < 4; ++j) {
            int row_l = r0 + mi * 16 + (lane >> 4) * 4 + j;
            float ss = 0.f;
            #pragma unroll
            for (int ni = 0; ni < 4; ++ni) {
                float y = fmaxf(acc[mi][ni][j] + bbv[ni], 0.f);
                ss += y * y;
            }
            ss += __shfl_xor(ss, 1); ss += __shfl_xor(ss, 2);
            ss += __shfl_xor(ss, 4); ss += __shfl_xor(ss, 8);
            if (lr == 0) atomicAdd(&rowss[row_l], ss);
        }
    }
    __syncthreads();
    #pragma unroll
    for (int mi = 0; mi < 2; ++mi) {
        #pragma unroll
        for (int j = 0; j < 4; ++j) {
            int row_l = r0 + mi * 16 + (lane >> 4) * 4 + j;
            int grow = n0 + row_l;
            if (grow < M) {
                float inv = 1.0f / fmaxf(sqrtf(rowss[row_l]), 1e-12f);
                #pragma unroll
                for (int ni = 0; ni < 4; ++ni) {
                    float y = fmaxf(acc[mi][ni][j] + bbv[ni], 0.f);
                    out[(size_t)grow * 128 + c0 + ni * 16 + lr] = y * inv;
                }
            }
        }
    }
}

extern "C" void kernel_launch(void* const* d_in, const int* in_sizes, int n_in,
                              void* d_out, int out_size, void* d_ws, size_t ws_size,
                              hipStream_t stream) {
    FP4 X  = {{(const float*)d_in[0], (const float*)d_in[2],
               (const float*)d_in[4], (const float*)d_in[6]}};
    IP4 ED = {{(const int*)d_in[1], (const int*)d_in[3],
               (const int*)d_in[5], (const int*)d_in[7]}};
    const float* xn = (const float*)d_in[8];
    FP4 Wm = {{(const float*)d_in[10], (const float*)d_in[12],
               (const float*)d_in[14], (const float*)d_in[16]}};
    FP4 Bv = {{(const float*)d_in[11], (const float*)d_in[13],
               (const float*)d_in[15], (const float*)d_in[17]}};
    const float* u  = (const float*)d_in[18];
    const float* Wl = (const float*)d_in[19];
    const float* bl = (const float*)d_in[20];
    float* out = (float*)d_out;

    const int N = in_sizes[8] / 128;
    int E[4];
    for (int r = 0; r < 4; ++r) E[r] = in_sizes[1 + 2 * r] / 2;
    const int4 Ev = make_int4(E[0], E[1], E[2], E[3]);
    const int nb1 = (N + BN1 - 1) / BN1;
    int maxE = 0;
    for (int r = 0; r < 4; ++r) maxE = (E[r] > maxE) ? E[r] : maxE;

    // ws layout
    unsigned char* h8 = (unsigned char*)d_ws;                    // 4*N*128 bytes
    char*  ubase   = (char*)(h8 + (size_t)4 * N * 128);
    int*   staging = (int*)ubase;                                // 4*nb1*BCAP1 ints
    __half* comb   = (__half*)ubase;                             // N*128 halfs (alias)
    size_t usz = (size_t)4 * nb1 * BCAP1 * sizeof(int);
    size_t csz = (size_t)N * 128 * sizeof(__half);
    char*  after   = ubase + (usz > csz ? usz : csz);
    __half* Wt     = (__half*)after;                             // 4*16384 halfs
    __half* Wlt    = Wt + (size_t)4 * 16384;                     // 128*256 halfs
    int2* offc   = (int2*)(Wlt + (size_t)128 * 256);             // 4*N int2
    int* bcur    = (int*)(offc + (size_t)4 * N);                 // 4*nb1*16
    int* gcur    = bcur + (size_t)4 * nb1 * 16;                  // 16 (pad)
    unsigned short* sorted = (unsigned short*)(gcur + 16);       // sumE ushorts

    const int gb = (N + 63) / 64;
    const int binb = (maxE + BLK_E - 1) / BLK_E;

    prep0_k<<<448, 256, 0, stream>>>(Wm, Wl, Wt, Wlt, bcur, 4 * nb1 * 16 + 16);
    binGemm_k<<<4 * binb + 4 * gb, 256, 0, stream>>>(ED, Ev, bcur, staging, nb1, binb,
                                                     X, Wt, Bv, h8, N, gb);
    csr2_k<<<dim3(nb1, 4), 256, 0, stream>>>(staging, bcur, gcur, offc, sorted, nb1, N);
    gather_attn_k<<<(N + 3) / 4, 256, 0, stream>>>(h8, xn, u, offc, sorted, comb, N);
    gemm_out_k<<<gb, 256, 0, stream>>>(xn, comb, Wlt, bl, out, N);
}